// Round 13
// baseline (63.552 us; speedup 1.0000x reference)
//
#include <hip/hip_runtime.h>

#define WL 512   // window_len (t and o dims)
#define NV 64    // n_var
#define LR 16    // low rank
#define NB 512   // batch
#define BI 16    // batches per k_out block

__device__ __forceinline__ float tanh_fast(float x) {
    // tanh(x) = 1 - 2/(exp(2x)+1); exact at +-inf saturation, ~1e-7 abs err
    float e = __expf(2.0f * x);
    return 1.0f - 2.0f / (e + 1.0f);
}

// K1: tmp[b,k,v] = sum_t tanh(g[v]*x[b,t,v]) * A[t,k]
// grid = 512 (one block per b), block = 1024 threads (16 waves).
// (byte-identical to R7's verified version; ~13.5us standalone)
__global__ __launch_bounds__(1024, 8) void k_tmp(
    const float* __restrict__ x, const float* __restrict__ gating,
    const float* __restrict__ A, float* __restrict__ tmp)
{
    __shared__ float red[16 * LR * NV];  // 64 KiB (16 partials x 1024 (k,v))
    const int tid = threadIdx.x;
    const int b = blockIdx.x;

    const int v = tid & 63;
    const int tg = __builtin_amdgcn_readfirstlane(tid >> 6);
    const float g = gating[v];

    float acc[LR];
#pragma unroll
    for (int k = 0; k < LR; ++k) acc[k] = 0.f;

    const float* xb = x + (size_t)b * (WL * NV) + (size_t)tg * 32 * NV + v;
    const float* Abase = A + (size_t)tg * 32 * LR;

#pragma unroll 4
    for (int i = 0; i < 32; ++i) {
        const float x1 = tanh_fast(g * xb[i * NV]);      // 256B/wave, coalesced
        const float* Ar = Abase + i * LR;                // wave-uniform -> s_load
#pragma unroll
        for (int k = 0; k < LR; ++k) acc[k] = fmaf(x1, Ar[k], acc[k]);
    }

#pragma unroll
    for (int k = 0; k < LR; ++k) red[(tg * LR + k) * NV + v] = acc[k];
    __syncthreads();

    {
        const int p = tid;
        float s = 0.f;
#pragma unroll
        for (int t = 0; t < 16; ++t) s += red[t * (LR * NV) + p];
        tmp[(size_t)b * (LR * NV) + p] = s;
    }
}

// K2: out[b,o,v] = x[b,o,v] + bias[o,v] + sum_k tmp[b,k,v]*B[k,o,v]
// grid = (32 b-chunks of 16) x (32 o-tiles of 16), block = 256 (4 waves)
//
// V-QUAD REMAP: every previous k_out stored 4B/lane (256B/wave). Here
// lane = (oL = lane>>4, vq = lane&15): lane owns o-row (wave_o0 + oL),
// v = vq*4..vq*4+3. x / bias / B-panel loads AND out stores are float4 =
// 1KB/wave fully contiguous (16B/lane sweet spot). Per wave per batch:
// 18 VMEM (16 tmp f4 + 1 x f4 + 1 store f4), was 32.
// B panel: Breg_f4[16] = 64 VGPR per lane, loaded once per block (1KB/wave
// per load); tmp double-buffered (128 VGPR). ~215 VGPR total under the
// waves_per_eu(2,2)-pinned 256 budget (the one config the allocator has
// honored: R10/R11). FMA order bias + k-ascending + x == previous rounds.
__global__ __attribute__((amdgpu_flat_work_group_size(256, 256),
                          amdgpu_waves_per_eu(2, 2)))
void k_out(
    const float* __restrict__ x, const float* __restrict__ bias,
    const float* __restrict__ Bm, const float* __restrict__ tmp,
    float* __restrict__ out)
{
    const int tid = threadIdx.x;
    const int lane = tid & 63;
    const int w = tid >> 6;                  // wave 0..3
    const int oL = lane >> 4;                // 0..3
    const int vq = lane & 15;                // v-quad: v = vq*4..vq*4+3
    const int o = blockIdx.y * 16 + w * 4 + oL;   // this lane's o-row
    const int b0 = blockIdx.x * BI;

    // B panel: lane's o-row, all 16 k, its v-quad. 1KB/wave per load.
    float4 Breg[LR];
#pragma unroll
    for (int k = 0; k < LR; ++k)
        Breg[k] = *(const float4*)(Bm + ((size_t)k * WL + o) * NV + vq * 4);

    const float4 bias4 = *(const float4*)(bias + (size_t)o * NV + vq * 4);

    // tmp double-buffer: 16 float4 per batch (256B/wave each, 4x lane-dup -> L1)
    float4 tA[LR], tB[LR];
    {
        const float* tb = tmp + (size_t)b0 * (LR * NV);
#pragma unroll
        for (int k = 0; k < LR; ++k) tA[k] = *(const float4*)(tb + k * NV + vq * 4);
    }

#pragma unroll 1
    for (int bl = 0; bl < BI; ++bl) {
        const int b = b0 + bl;

        // prefetch next batch's tmp row into the other buffer
        if (bl + 1 < BI) {
            const float* tb = tmp + (size_t)(b + 1) * (LR * NV);
#pragma unroll
            for (int k = 0; k < LR; ++k) tB[k] = *(const float4*)(tb + k * NV + vq * 4);
        }

        const float4 x4 = *(const float4*)(x + (size_t)b * (WL * NV) + (size_t)o * NV + vq * 4);

        float4 acc = bias4;
#pragma unroll
        for (int k = 0; k < LR; ++k) {
            acc.x = fmaf(tA[k].x, Breg[k].x, acc.x);
            acc.y = fmaf(tA[k].y, Breg[k].y, acc.y);
            acc.z = fmaf(tA[k].z, Breg[k].z, acc.z);
            acc.w = fmaf(tA[k].w, Breg[k].w, acc.w);
        }
        acc.x += x4.x; acc.y += x4.y; acc.z += x4.z; acc.w += x4.w;

        // 1KB/wave contiguous store
        *(float4*)(out + (size_t)b * (WL * NV) + (size_t)o * NV + vq * 4) = acc;

        if (bl + 1 < BI) {
#pragma unroll
            for (int k = 0; k < LR; ++k) tA[k] = tB[k];
        }
    }
}

extern "C" void kernel_launch(void* const* d_in, const int* in_sizes, int n_in,
                              void* d_out, int out_size, void* d_ws, size_t ws_size,
                              hipStream_t stream) {
    const float* x      = (const float*)d_in[0];  // [512,512,64,1]
    const float* gating = (const float*)d_in[1];  // [64]
    const float* bias   = (const float*)d_in[2];  // [512,64]
    const float* A      = (const float*)d_in[3];  // [512,16]
    const float* Bm     = (const float*)d_in[4];  // [16,512,64]
    float* out = (float*)d_out;
    float* tmp = (float*)d_ws;                    // 2 MiB scratch ([b,k,v])

    k_tmp<<<NB, 1024, 0, stream>>>(x, gating, A, tmp);
    k_out<<<dim3(32, 32), 256, 0, stream>>>(x, bias, Bm, tmp, out);
}